// Round 10
// baseline (260.842 us; speedup 1.0000x reference)
//
#include <hip/hip_runtime.h>
#include <stdint.h>

typedef float f32x4 __attribute__((ext_vector_type(4)));
typedef int   i32x4 __attribute__((ext_vector_type(4)));
typedef __bf16 bf16x8 __attribute__((ext_vector_type(8)));

#define NN 8192
#define DDIM 128
#define RSTRIDE 144   // tile row: hi 64B | lo 64B | 16B pad  (16B-aligned rows)

// LDS byte offsets: two combined tiles (A, B) + aux
#define OFF_A   0
#define OFF_B   18432
#define OFF_ILS 36864
#define OFF_N1  37376
#define OFF_N2  37888
#define LDS_TOT 38400   // 38.4 KB -> 4 blocks/CU (153.6 KB of 160 KB)

__device__ __forceinline__ uint32_t pk2(__bf16 a, __bf16 b) {
    return (uint32_t)__builtin_bit_cast(unsigned short, a)
         | ((uint32_t)__builtin_bit_cast(unsigned short, b) << 16);
}

// RNE hi/lo split of 4 scaled f32 (verified R3/R5/R6/R7)
__device__ __forceinline__ void split4(f32x4 x, uint2& hi, uint2& lo) {
    __bf16 h0 = (__bf16)x[0], h1 = (__bf16)x[1], h2 = (__bf16)x[2], h3 = (__bf16)x[3];
    hi.x = pk2(h0, h1); hi.y = pk2(h2, h3);
    __bf16 l0 = (__bf16)(x[0] - (float)h0);
    __bf16 l1 = (__bf16)(x[1] - (float)h1);
    __bf16 l2 = (__bf16)(x[2] - (float)h2);
    __bf16 l3 = (__bf16)(x[3] - (float)h3);
    lo.x = pk2(l0, l1); lo.y = pk2(l2, l3);
}

// LDS-visibility-only barrier: does NOT drain vmcnt (verified R7).
__device__ __forceinline__ void lds_barrier() {
    asm volatile("s_waitcnt lgkmcnt(0)" ::: "memory");
    __builtin_amdgcn_sched_barrier(0);
    __builtin_amdgcn_s_barrier();
    __builtin_amdgcn_sched_barrier(0);
}

// Fused TGP: split-once-to-LDS bf16 3-term GEMM + in-LDS norms + fused epilogue.
// 128x128 tile, 256 thr (2x2 waves of 64x64), BK=32, single-buffered combined
// tiles, 2 lds_barriers/chunk, 1-deep register prefetch across barriers.
// 4 blocks/CU (the R9 lesson: independent block-streams are the overlap source).
__global__ __launch_bounds__(256, 4) void tgp_kernel(
    const float* __restrict__ X1, const float* __restrict__ X2,
    const float* __restrict__ log_l,
    const float* __restrict__ log_theta_l, const float* __restrict__ bparam,
    const int* __restrict__ task1, const int* __restrict__ task2,
    float* __restrict__ C)
{
    __shared__ __align__(16) char smem[LDS_TOT];
    float* const ils = (float*)(smem + OFF_ILS);
    float* const n1s = (float*)(smem + OFF_N1);
    float* const n2s = (float*)(smem + OFF_N2);

    const int t = threadIdx.x;
    const int lane = t & 63;
    const int wv = t >> 6;
    const int wr = wv >> 1, wc = wv & 1;
    const int lr = lane & 15, lg = lane >> 4;
    const int kq = t & 7;     // 8-B col unit within 32-col chunk
    const int rg = t >> 3;    // 0..31 row within each 32-row stripe

    // L2 super-tile ordering (verified R7): XCD x owns A-row band x, sweeps
    // B in 8-tile super-columns. Bijective for nwg=4096.
    int wg = blockIdx.x;
    int xcd = wg & 7;
    int r = wg >> 3;
    int su = r >> 6;
    int inner = r & 63;
    int tm = xcd * 8 + (inner >> 3);
    int tn = su * 8 + (inner & 7);

    const float* Ag = X1 + (size_t)tm * 128 * DDIM;
    const float* Bg = X2 + (size_t)tn * 128 * DDIM;

    f32x4 aV[4], bV[4];
    #define LOADC(c) do {                                                        \
        _Pragma("unroll")                                                        \
        for (int e = 0; e < 4; ++e) {                                            \
            aV[e] = *(const f32x4*)(Ag + (size_t)(e * 32 + rg) * DDIM + (c) * 32 + kq * 4); \
            bV[e] = *(const f32x4*)(Bg + (size_t)(e * 32 + rg) * DDIM + (c) * 32 + kq * 4); \
        }                                                                        \
    } while (0)

    float nA[4] = {0.f, 0.f, 0.f, 0.f};
    float nB[4] = {0.f, 0.f, 0.f, 0.f};

    // scale, norm partial, RNE hi/lo split, ds_write into combined tiles
    #define SPLITW(c) do {                                                       \
        f32x4 il4 = *(const f32x4*)(ils + (c) * 32 + kq * 4);                    \
        _Pragma("unroll")                                                        \
        for (int e = 0; e < 4; ++e) {                                            \
            int row = e * 32 + rg;                                               \
            f32x4 xa = aV[e] * il4;                                              \
            f32x4 xb = bV[e] * il4;                                              \
            nA[e] += xa[0]*xa[0] + xa[1]*xa[1] + xa[2]*xa[2] + xa[3]*xa[3];      \
            nB[e] += xb[0]*xb[0] + xb[1]*xb[1] + xb[2]*xb[2] + xb[3]*xb[3];      \
            uint2 hA, lA, hB, lB;                                                \
            split4(xa, hA, lA);                                                  \
            split4(xb, hB, lB);                                                  \
            int boff = row * RSTRIDE + kq * 8;                                   \
            *(uint2*)(smem + OFF_A + boff)      = hA;                            \
            *(uint2*)(smem + OFF_A + boff + 64) = lA;                            \
            *(uint2*)(smem + OFF_B + boff)      = hB;                            \
            *(uint2*)(smem + OFF_B + boff + 64) = lB;                            \
        }                                                                        \
    } while (0)

    f32x4 acc[4][4];
    #pragma unroll
    for (int i = 0; i < 4; ++i)
        #pragma unroll
        for (int j = 0; j < 4; ++j) acc[i][j] = (f32x4){0.f, 0.f, 0.f, 0.f};

    // fragment reads + 48 MFMA (3-term, swapped operands)
    #define FRAGMM() do {                                                        \
        bf16x8 ah[4], bh[4], xf[4];                                              \
        _Pragma("unroll")                                                        \
        for (int mi = 0; mi < 4; ++mi) {                                         \
            int off = (wr * 64 + mi * 16 + lr) * RSTRIDE + lg * 16;              \
            ah[mi] = *(const bf16x8*)(smem + OFF_A + off);                       \
        }                                                                        \
        _Pragma("unroll")                                                        \
        for (int ni = 0; ni < 4; ++ni) {                                         \
            int off = (wc * 64 + ni * 16 + lr) * RSTRIDE + lg * 16;              \
            bh[ni] = *(const bf16x8*)(smem + OFF_B + off);                       \
        }                                                                        \
        _Pragma("unroll")                                                        \
        for (int mi = 0; mi < 4; ++mi)                                           \
            _Pragma("unroll")                                                    \
            for (int ni = 0; ni < 4; ++ni)                                       \
                acc[mi][ni] = __builtin_amdgcn_mfma_f32_16x16x32_bf16(bh[ni], ah[mi], acc[mi][ni], 0, 0, 0); \
        _Pragma("unroll")                                                        \
        for (int mi = 0; mi < 4; ++mi) {                                         \
            int off = (wr * 64 + mi * 16 + lr) * RSTRIDE + lg * 16;              \
            xf[mi] = *(const bf16x8*)(smem + OFF_A + off + 64);                  \
        }                                                                        \
        _Pragma("unroll")                                                        \
        for (int mi = 0; mi < 4; ++mi)                                           \
            _Pragma("unroll")                                                    \
            for (int ni = 0; ni < 4; ++ni)                                       \
                acc[mi][ni] = __builtin_amdgcn_mfma_f32_16x16x32_bf16(bh[ni], xf[mi], acc[mi][ni], 0, 0, 0); \
        _Pragma("unroll")                                                        \
        for (int ni = 0; ni < 4; ++ni) {                                         \
            int off = (wc * 64 + ni * 16 + lr) * RSTRIDE + lg * 16;              \
            xf[ni] = *(const bf16x8*)(smem + OFF_B + off + 64);                  \
        }                                                                        \
        _Pragma("unroll")                                                        \
        for (int mi = 0; mi < 4; ++mi)                                           \
            _Pragma("unroll")                                                    \
            for (int ni = 0; ni < 4; ++ni)                                       \
                acc[mi][ni] = __builtin_amdgcn_mfma_f32_16x16x32_bf16(xf[ni], ah[mi], acc[mi][ni], 0, 0, 0); \
    } while (0)

    // ---- prologue ----
    LOADC(0);
    if (t < 128) ils[t] = __expf(-log_l[t]);
    __syncthreads();   // ils visible

    // ---- main loop (R7 structure): 2 lds_barriers/chunk, prefetch in flight ----
    for (int c = 0; c < 4; ++c) {
        SPLITW(c);
        if (c < 3) LOADC(c + 1);   // stays in flight across both barriers
        lds_barrier();             // split tiles visible; vmcnt NOT drained
        FRAGMM();
        lds_barrier();             // reads done before next overwrite
    }
    #undef LOADC
    #undef SPLITW
    #undef FRAGMM

    // ---- norm reduce: 8-lane groups over kq; lane kq==0 owns row rg ----
    #pragma unroll
    for (int e = 0; e < 4; ++e) {
        #pragma unroll
        for (int off = 1; off < 8; off <<= 1) {
            nA[e] += __shfl_xor(nA[e], off);
            nB[e] += __shfl_xor(nB[e], off);
        }
    }
    if (kq == 0) {
        #pragma unroll
        for (int e = 0; e < 4; ++e) {
            n1s[e * 32 + rg] = nA[e];
            n2s[e * 32 + rg] = nB[e];
        }
    }
    __syncthreads();   // norms visible

    // ---- epilogue (verified mapping): lane lr = A-row slice,
    //      reg r = 4 consecutive cols at lg*4 (swapped operands) ----
    float logt = log_theta_l[0];
    float bb = bparam[0];
    float lam = fminf(fmaxf(2.f / (1.f + __expf(bb)) - 1.f, 0.f), 1.f);
    int rbase = tm * 128, cbase = tn * 128;

    #pragma unroll
    for (int mi = 0; mi < 4; ++mi) {
        int rowl = wr * 64 + mi * 16 + lr;
        float n1v = n1s[rowl];
        int t1v = task1[rbase + rowl];
        #pragma unroll
        for (int ni = 0; ni < 4; ++ni) {
            int coll = wc * 64 + ni * 16 + lg * 4;
            f32x4 n2v = *(const f32x4*)(n2s + coll);
            i32x4 t2v = *(const i32x4*)(task2 + cbase + coll);
            f32x4 kv;
            #pragma unroll
            for (int rix = 0; rix < 4; ++rix) {
                float s = fmaxf(n1v + n2v[rix] - 2.f * acc[mi][ni][rix], 0.f);
                float k = __expf(fmaf(-0.5f, s, logt));
                kv[rix] = (t1v != t2v[rix]) ? k * lam : k;
            }
            // streaming output: nontemporal, keeps L2 for A/B panels
            __builtin_nontemporal_store(kv,
                (f32x4*)(C + (size_t)(rbase + rowl) * NN + cbase + coll));
        }
    }
}

extern "C" void kernel_launch(void* const* d_in, const int* in_sizes, int n_in,
                              void* d_out, int out_size, void* d_ws, size_t ws_size,
                              hipStream_t stream)
{
    const float* X1 = (const float*)d_in[0];
    const float* X2 = (const float*)d_in[1];
    const float* log_l = (const float*)d_in[2];
    const float* log_theta = (const float*)d_in[3];
    const float* bp = (const float*)d_in[4];
    const int* t1 = (const int*)d_in[5];
    const int* t2 = (const int*)d_in[6];
    float* C = (float*)d_out;
    (void)d_ws; (void)ws_size; (void)in_sizes; (void)n_in; (void)out_size;

    tgp_kernel<<<4096, 256, 0, stream>>>(X1, X2, log_l, log_theta, bp, t1, t2, C);
}

// Round 11
// 260.256 us; speedup vs baseline: 1.0023x; 1.0023x over previous
//
#include <hip/hip_runtime.h>
#include <stdint.h>

typedef float f32x4 __attribute__((ext_vector_type(4)));
typedef int   i32x4 __attribute__((ext_vector_type(4)));
typedef __bf16 bf16x8 __attribute__((ext_vector_type(8)));

#define NN 8192
#define DDIM 128

// Fused TGP, zero-barrier K-loop (R5 dataflow, verified): each wave owns a
// 64x64 quadrant, loads its fragments straight from global (L2-resident via
// R7-verified super-tile ordering), RNE hi/lo splits in-register, 3-term
// swapped-operand MFMA, register prefetch one chunk deep between MFMA terms.
// LDS only for ils + norms. 3 blocks/CU (~170 reg cap).
__global__ __launch_bounds__(256, 3) void tgp_kernel(
    const float* __restrict__ X1, const float* __restrict__ X2,
    const float* __restrict__ log_l,
    const float* __restrict__ log_theta_l, const float* __restrict__ bparam,
    const int* __restrict__ task1, const int* __restrict__ task2,
    float* __restrict__ C)
{
    __shared__ float ils[128];
    __shared__ float n1s[128];
    __shared__ float n2s[128];

    const int t = threadIdx.x;
    const int lane = t & 63;
    const int wv = t >> 6;
    const int wr = wv >> 1, wc = wv & 1;   // 2x2 waves, 64x64 each
    const int lr = lane & 15, lg = lane >> 4;

    // L2 super-tile ordering (verified R7/R9): XCD x owns A-row band x,
    // sweeps B in 8-tile super-columns. Bijective for nwg=4096.
    int wg = blockIdx.x;
    int xcd = wg & 7;
    int r = wg >> 3;
    int su = r >> 6;
    int inner = r & 63;
    int tm = xcd * 8 + (inner >> 3);
    int tn = su * 8 + (inner & 7);

    const float* Ag = X1 + (size_t)tm * 128 * DDIM;
    const float* Bg = X2 + (size_t)tn * 128 * DDIM;

    if (t < 128) ils[t] = __expf(-log_l[t]);
    __syncthreads();   // ils visible (only barrier before epilogue sync)

    // per-lane element indices (32-bit; compiler uses saddr + voffset form)
    int idxA[4], idxB[4];
    #pragma unroll
    for (int mi = 0; mi < 4; ++mi) {
        idxA[mi] = (wr * 64 + mi * 16 + lr) * DDIM + lg * 8;
        idxB[mi] = (wc * 64 + mi * 16 + lr) * DDIM + lg * 8;
    }

    f32x4 acc[4][4];
    #pragma unroll
    for (int i = 0; i < 4; ++i)
        #pragma unroll
        for (int j = 0; j < 4; ++j) acc[i][j] = (f32x4){0.f, 0.f, 0.f, 0.f};

    float nA[4] = {0.f, 0.f, 0.f, 0.f};
    float nB[4] = {0.f, 0.f, 0.f, 0.f};

    // prologue: raw loads for chunk 0
    f32x4 xa[4][2], xb[4][2];
    #pragma unroll
    for (int mi = 0; mi < 4; ++mi) {
        xa[mi][0] = *(const f32x4*)(Ag + idxA[mi]);
        xa[mi][1] = *(const f32x4*)(Ag + idxA[mi] + 4);
        xb[mi][0] = *(const f32x4*)(Bg + idxB[mi]);
        xb[mi][1] = *(const f32x4*)(Bg + idxB[mi] + 4);
    }

    #pragma unroll
    for (int c = 0; c < 4; ++c) {
        f32x4 il0 = *(const f32x4*)(ils + c * 32 + lg * 8);
        f32x4 il1 = *(const f32x4*)(ils + c * 32 + lg * 8 + 4);

        bf16x8 ah[4], al[4], bh[4], bl[4];
        #pragma unroll
        for (int mi = 0; mi < 4; ++mi) {
            f32x4 x0 = xa[mi][0] * il0, x1 = xa[mi][1] * il1;
            nA[mi] += x0[0]*x0[0] + x0[1]*x0[1] + x0[2]*x0[2] + x0[3]*x0[3]
                    + x1[0]*x1[0] + x1[1]*x1[1] + x1[2]*x1[2] + x1[3]*x1[3];
            #pragma unroll
            for (int e = 0; e < 4; ++e) {
                __bf16 h0 = (__bf16)x0[e];
                ah[mi][e] = h0;
                al[mi][e] = (__bf16)(x0[e] - (float)h0);
                __bf16 h1 = (__bf16)x1[e];
                ah[mi][e + 4] = h1;
                al[mi][e + 4] = (__bf16)(x1[e] - (float)h1);
            }
            f32x4 y0 = xb[mi][0] * il0, y1 = xb[mi][1] * il1;
            nB[mi] += y0[0]*y0[0] + y0[1]*y0[1] + y0[2]*y0[2] + y0[3]*y0[3]
                    + y1[0]*y1[0] + y1[1]*y1[1] + y1[2]*y1[2] + y1[3]*y1[3];
            #pragma unroll
            for (int e = 0; e < 4; ++e) {
                __bf16 h0 = (__bf16)y0[e];
                bh[mi][e] = h0;
                bl[mi][e] = (__bf16)(y0[e] - (float)h0);
                __bf16 h1 = (__bf16)y1[e];
                bh[mi][e + 4] = h1;
                bl[mi][e + 4] = (__bf16)(y1[e] - (float)h1);
            }
        }

        // term 1: hi x hi
        #pragma unroll
        for (int mi = 0; mi < 4; ++mi)
            #pragma unroll
            for (int ni = 0; ni < 4; ++ni)
                acc[mi][ni] = __builtin_amdgcn_mfma_f32_16x16x32_bf16(bh[ni], ah[mi], acc[mi][ni], 0, 0, 0);

        if (c < 3) {   // prefetch A(c+1); hides under term-2/3 MFMA issue
            #pragma unroll
            for (int mi = 0; mi < 4; ++mi) {
                xa[mi][0] = *(const f32x4*)(Ag + idxA[mi] + (c + 1) * 32);
                xa[mi][1] = *(const f32x4*)(Ag + idxA[mi] + (c + 1) * 32 + 4);
            }
        }

        // term 2: lo(A) x hi(B)   (bh dies after this)
        #pragma unroll
        for (int mi = 0; mi < 4; ++mi)
            #pragma unroll
            for (int ni = 0; ni < 4; ++ni)
                acc[mi][ni] = __builtin_amdgcn_mfma_f32_16x16x32_bf16(bh[ni], al[mi], acc[mi][ni], 0, 0, 0);

        if (c < 3) {   // prefetch B(c+1)
            #pragma unroll
            for (int mi = 0; mi < 4; ++mi) {
                xb[mi][0] = *(const f32x4*)(Bg + idxB[mi] + (c + 1) * 32);
                xb[mi][1] = *(const f32x4*)(Bg + idxB[mi] + (c + 1) * 32 + 4);
            }
        }

        // term 3: hi(A) x lo(B)
        #pragma unroll
        for (int mi = 0; mi < 4; ++mi)
            #pragma unroll
            for (int ni = 0; ni < 4; ++ni)
                acc[mi][ni] = __builtin_amdgcn_mfma_f32_16x16x32_bf16(bl[ni], ah[mi], acc[mi][ni], 0, 0, 0);
    }

    // ---- norm reduce across lg groups (verified R5) ----
    #pragma unroll
    for (int mi = 0; mi < 4; ++mi) {
        nA[mi] += __shfl_xor(nA[mi], 16);
        nA[mi] += __shfl_xor(nA[mi], 32);
        nB[mi] += __shfl_xor(nB[mi], 16);
        nB[mi] += __shfl_xor(nB[mi], 32);
    }
    if (wc == 0 && lg == 0) {
        #pragma unroll
        for (int mi = 0; mi < 4; ++mi) n1s[wr * 64 + mi * 16 + lr] = nA[mi];
    }
    if (wr == 0 && lg == 0) {
        #pragma unroll
        for (int ni = 0; ni < 4; ++ni) n2s[wc * 64 + ni * 16 + lr] = nB[ni];
    }
    __syncthreads();   // norms visible

    // ---- epilogue (verified mapping): lane lr = A-row slice,
    //      reg r = 4 consecutive cols at lg*4 (swapped operands); NT stores ----
    float logt = log_theta_l[0];
    float bb = bparam[0];
    float lam = fminf(fmaxf(2.f / (1.f + __expf(bb)) - 1.f, 0.f), 1.f);
    int rbase = tm * 128, cbase = tn * 128;

    #pragma unroll
    for (int mi = 0; mi < 4; ++mi) {
        int rowl = wr * 64 + mi * 16 + lr;
        float n1v = n1s[rowl];
        int t1v = task1[rbase + rowl];
        #pragma unroll
        for (int ni = 0; ni < 4; ++ni) {
            int coll = wc * 64 + ni * 16 + lg * 4;
            f32x4 n2v = *(const f32x4*)(n2s + coll);
            i32x4 t2v = *(const i32x4*)(task2 + cbase + coll);
            f32x4 kv;
            #pragma unroll
            for (int rix = 0; rix < 4; ++rix) {
                float s = fmaxf(n1v + n2v[rix] - 2.f * acc[mi][ni][rix], 0.f);
                float k = __expf(fmaf(-0.5f, s, logt));
                kv[rix] = (t1v != t2v[rix]) ? k * lam : k;
            }
            __builtin_nontemporal_store(kv,
                (f32x4*)(C + (size_t)(rbase + rowl) * NN + cbase + coll));
        }
    }
}

extern "C" void kernel_launch(void* const* d_in, const int* in_sizes, int n_in,
                              void* d_out, int out_size, void* d_ws, size_t ws_size,
                              hipStream_t stream)
{
    const float* X1 = (const float*)d_in[0];
    const float* X2 = (const float*)d_in[1];
    const float* log_l = (const float*)d_in[2];
    const float* log_theta = (const float*)d_in[3];
    const float* bp = (const float*)d_in[4];
    const int* t1 = (const int*)d_in[5];
    const int* t2 = (const int*)d_in[6];
    float* C = (float*)d_out;
    (void)d_ws; (void)ws_size; (void)in_sizes; (void)n_in; (void)out_size;

    tgp_kernel<<<4096, 256, 0, stream>>>(X1, X2, log_l, log_theta, bp, t1, t2, C);
}

// Round 12
// 140.681 us; speedup vs baseline: 1.8541x; 1.8500x over previous
//
#include <hip/hip_runtime.h>
#include <stdint.h>

typedef float f32x4 __attribute__((ext_vector_type(4)));
typedef int   i32x4 __attribute__((ext_vector_type(4)));
typedef __bf16 bf16x8 __attribute__((ext_vector_type(8)));

#define NN 8192
#define DDIM 128
#define RSTRIDE 80   // padded LDS row stride: 32 bf16 (64 B) + 16 B pad

// LDS byte offsets (single-buffered split tiles, R7 layout verbatim)
#define OFF_AH 0
#define OFF_AL 10240
#define OFF_BH 20480
#define OFF_BL 30720
#define OFF_ILS 40960
#define OFF_N1  41472
#define OFF_N2  41984
#define LDS_TOT 42496

__device__ __forceinline__ uint32_t pk2(__bf16 a, __bf16 b) {
    return (uint32_t)__builtin_bit_cast(unsigned short, a)
         | ((uint32_t)__builtin_bit_cast(unsigned short, b) << 16);
}

// RNE hi/lo split of 4 scaled f32 (verified R3/R5/R6/R7)
__device__ __forceinline__ void split4(f32x4 x, uint2& hi, uint2& lo) {
    __bf16 h0 = (__bf16)x[0], h1 = (__bf16)x[1], h2 = (__bf16)x[2], h3 = (__bf16)x[3];
    hi.x = pk2(h0, h1); hi.y = pk2(h2, h3);
    __bf16 l0 = (__bf16)(x[0] - (float)h0);
    __bf16 l1 = (__bf16)(x[1] - (float)h1);
    __bf16 l2 = (__bf16)(x[2] - (float)h2);
    __bf16 l3 = (__bf16)(x[3] - (float)h3);
    lo.x = pk2(l0, l1); lo.y = pk2(l2, l3);
}

// LDS-visibility-only barrier: does NOT drain vmcnt (verified R7).
__device__ __forceinline__ void lds_barrier() {
    asm volatile("s_waitcnt lgkmcnt(0)" ::: "memory");
    __builtin_amdgcn_sched_barrier(0);
    __builtin_amdgcn_s_barrier();
    __builtin_amdgcn_sched_barrier(0);
}

// Fused TGP: R7 structure x 4 output tiles per block.
// 128x128 tile, 256 thr (2x2 waves of 64x64), BK=32, single-buffered split
// tiles, 2 lds_barriers/chunk, register prefetch in flight across barriers.
// Each block: fixed tm, tiles tn = tnb..tnb+3; tile j's stores drain under
// tile j+1's compute (store/compute overlap without touching the sync class).
__global__ __launch_bounds__(256, 3) void tgp_kernel(
    const float* __restrict__ X1, const float* __restrict__ X2,
    const float* __restrict__ log_l,
    const float* __restrict__ log_theta_l, const float* __restrict__ bparam,
    const int* __restrict__ task1, const int* __restrict__ task2,
    float* __restrict__ C)
{
    __shared__ __align__(16) char smem[LDS_TOT];
    float* const ils = (float*)(smem + OFF_ILS);
    float* const n1s = (float*)(smem + OFF_N1);
    float* const n2s = (float*)(smem + OFF_N2);

    const int t = threadIdx.x;
    const int lane = t & 63;
    const int wv = t >> 6;
    const int wr = wv >> 1, wc = wv & 1;
    const int lr = lane & 15, lg = lane >> 4;
    const int kq = t & 7;     // 8-B col unit within 32-col chunk
    const int rg = t >> 3;    // 0..31 row within each 32-row stripe

    // 4-tile super-block mapping (grid = 1024, bijective):
    // XCD x owns A-row band x (as verified R7); B swept in 8-col super-tiles;
    // block handles (tm, tnb..tnb+3) with B tiles contiguous in memory.
    int wg = blockIdx.x;
    int xcd = wg & 7;
    int r = wg >> 3;            // 0..127
    int su = r >> 4;            // 0..7
    int inner = r & 15;
    int tm = xcd * 8 + (inner >> 1);
    int tnb = su * 8 + (inner & 1) * 4;

    const float* Ag = X1 + (size_t)tm * 128 * DDIM;
    const float* Bg = X2 + (size_t)tnb * 128 * DDIM;

    if (t < 128) ils[t] = __expf(-log_l[t]);

    // prologue: tile 0, chunk 0 loads
    f32x4 aV[4], bV[4];
    #pragma unroll
    for (int e = 0; e < 4; ++e) {
        aV[e] = *(const f32x4*)(Ag + (size_t)(e * 32 + rg) * DDIM + kq * 4);
        bV[e] = *(const f32x4*)(Bg + (size_t)(e * 32 + rg) * DDIM + kq * 4);
    }
    __syncthreads();   // ils visible

    float nA[4] = {0.f, 0.f, 0.f, 0.f};
    float n1r[4]; int t1r[4];          // hoisted per-row epilogue constants
    float logt = log_theta_l[0];
    float bb = bparam[0];
    float lam = fminf(fmaxf(2.f / (1.f + __expf(bb)) - 1.f, 0.f), 1.f);
    int rbase = tm * 128;

    for (int j = 0; j < 4; ++j) {
        f32x4 acc[4][4];
        #pragma unroll
        for (int i = 0; i < 4; ++i)
            #pragma unroll
            for (int k = 0; k < 4; ++k) acc[i][k] = (f32x4){0.f, 0.f, 0.f, 0.f};
        float nB[4] = {0.f, 0.f, 0.f, 0.f};

        for (int c = 0; c < 4; ++c) {
            // ---- split-write: scale, norm partial, RNE hi/lo, ds_write ----
            {
                f32x4 il4 = *(const f32x4*)(ils + c * 32 + kq * 4);
                #pragma unroll
                for (int e = 0; e < 4; ++e) {
                    int row = e * 32 + rg;
                    f32x4 xa = aV[e] * il4;
                    f32x4 xb = bV[e] * il4;
                    if (j == 0)
                        nA[e] += xa[0]*xa[0] + xa[1]*xa[1] + xa[2]*xa[2] + xa[3]*xa[3];
                    nB[e] += xb[0]*xb[0] + xb[1]*xb[1] + xb[2]*xb[2] + xb[3]*xb[3];
                    uint2 hA, lA, hB, lB;
                    split4(xa, hA, lA);
                    split4(xb, hB, lB);
                    int boff = row * RSTRIDE + kq * 8;
                    *(uint2*)(smem + OFF_AH + boff) = hA;
                    *(uint2*)(smem + OFF_AL + boff) = lA;
                    *(uint2*)(smem + OFF_BH + boff) = hB;
                    *(uint2*)(smem + OFF_BL + boff) = lB;
                }
            }
            // ---- prefetch: next chunk, or next tile's chunk 0 (B is +16384) ----
            if (c < 3) {
                #pragma unroll
                for (int e = 0; e < 4; ++e) {
                    aV[e] = *(const f32x4*)(Ag + (size_t)(e * 32 + rg) * DDIM + (c + 1) * 32 + kq * 4);
                    bV[e] = *(const f32x4*)(Bg + (size_t)(e * 32 + rg) * DDIM + (c + 1) * 32 + kq * 4);
                }
            } else if (j < 3) {
                #pragma unroll
                for (int e = 0; e < 4; ++e) {
                    aV[e] = *(const f32x4*)(Ag + (size_t)(e * 32 + rg) * DDIM + kq * 4);
                    bV[e] = *(const f32x4*)(Bg + 16384 + (size_t)(e * 32 + rg) * DDIM + kq * 4);
                }
            }
            // ---- norms complete at chunk 3: reduce over kq, stage to LDS ----
            if (c == 3) {
                #pragma unroll
                for (int e = 0; e < 4; ++e) {
                    #pragma unroll
                    for (int off = 1; off < 8; off <<= 1) {
                        nB[e] += __shfl_xor(nB[e], off);
                        if (j == 0) nA[e] += __shfl_xor(nA[e], off);
                    }
                }
                if (kq == 0) {
                    #pragma unroll
                    for (int e = 0; e < 4; ++e) {
                        n2s[e * 32 + rg] = nB[e];
                        if (j == 0) n1s[e * 32 + rg] = nA[e];
                    }
                }
            }
            lds_barrier();   // split tiles (+ norms at c==3) visible; vmcnt NOT drained

            // ---- fragment reads + 48 MFMA (3-term, swapped operands) ----
            {
                bf16x8 ah[4], bh[4], xf[4];
                #pragma unroll
                for (int mi = 0; mi < 4; ++mi) {
                    int off = (wr * 64 + mi * 16 + lr) * RSTRIDE + lg * 16;
                    ah[mi] = *(const bf16x8*)(smem + OFF_AH + off);
                }
                #pragma unroll
                for (int ni = 0; ni < 4; ++ni) {
                    int off = (wc * 64 + ni * 16 + lr) * RSTRIDE + lg * 16;
                    bh[ni] = *(const bf16x8*)(smem + OFF_BH + off);
                }
                #pragma unroll
                for (int mi = 0; mi < 4; ++mi)
                    #pragma unroll
                    for (int ni = 0; ni < 4; ++ni)
                        acc[mi][ni] = __builtin_amdgcn_mfma_f32_16x16x32_bf16(bh[ni], ah[mi], acc[mi][ni], 0, 0, 0);
                #pragma unroll
                for (int mi = 0; mi < 4; ++mi) {
                    int off = (wr * 64 + mi * 16 + lr) * RSTRIDE + lg * 16;
                    xf[mi] = *(const bf16x8*)(smem + OFF_AL + off);
                }
                #pragma unroll
                for (int mi = 0; mi < 4; ++mi)
                    #pragma unroll
                    for (int ni = 0; ni < 4; ++ni)
                        acc[mi][ni] = __builtin_amdgcn_mfma_f32_16x16x32_bf16(bh[ni], xf[mi], acc[mi][ni], 0, 0, 0);
                #pragma unroll
                for (int ni = 0; ni < 4; ++ni) {
                    int off = (wc * 64 + ni * 16 + lr) * RSTRIDE + lg * 16;
                    xf[ni] = *(const bf16x8*)(smem + OFF_BL + off);
                }
                #pragma unroll
                for (int mi = 0; mi < 4; ++mi)
                    #pragma unroll
                    for (int ni = 0; ni < 4; ++ni)
                        acc[mi][ni] = __builtin_amdgcn_mfma_f32_16x16x32_bf16(xf[ni], ah[mi], acc[mi][ni], 0, 0, 0);
            }
            lds_barrier();   // reads done before next overwrite
        }

        // ---- epilogue tile j (verified mapping); stores drain under tile j+1 ----
        int cbase = (tnb + j) * 128;
        #pragma unroll
        for (int mi = 0; mi < 4; ++mi) {
            int rowl = wr * 64 + mi * 16 + lr;
            if (j == 0) {
                n1r[mi] = n1s[rowl];
                t1r[mi] = task1[rbase + rowl];
            }
            #pragma unroll
            for (int ni = 0; ni < 4; ++ni) {
                int coll = wc * 64 + ni * 16 + lg * 4;
                f32x4 n2v = *(const f32x4*)(n2s + coll);
                i32x4 t2v = *(const i32x4*)(task2 + cbase + coll);
                f32x4 kv;
                #pragma unroll
                for (int rix = 0; rix < 4; ++rix) {
                    float s = fmaxf(n1r[mi] + n2v[rix] - 2.f * acc[mi][ni][rix], 0.f);
                    float k = __expf(fmaf(-0.5f, s, logt));
                    kv[rix] = (t1r[mi] != t2v[rix]) ? k * lam : k;
                }
                *(f32x4*)(C + (size_t)(rbase + rowl) * NN + cbase + coll) = kv;
            }
        }
        Bg += 128 * DDIM;   // next B tile (contiguous)
    }
}

extern "C" void kernel_launch(void* const* d_in, const int* in_sizes, int n_in,
                              void* d_out, int out_size, void* d_ws, size_t ws_size,
                              hipStream_t stream)
{
    const float* X1 = (const float*)d_in[0];
    const float* X2 = (const float*)d_in[1];
    const float* log_l = (const float*)d_in[2];
    const float* log_theta = (const float*)d_in[3];
    const float* bp = (const float*)d_in[4];
    const int* t1 = (const int*)d_in[5];
    const int* t2 = (const int*)d_in[6];
    float* C = (float*)d_out;
    (void)d_ws; (void)ws_size; (void)in_sizes; (void)n_in; (void)out_size;

    tgp_kernel<<<1024, 256, 0, stream>>>(X1, X2, log_l, log_theta, bp, t1, t2, C);
}

// Round 13
// 95.212 us; speedup vs baseline: 2.7396x; 1.4776x over previous
//
#include <hip/hip_runtime.h>
#include <stdint.h>

typedef float f32x4 __attribute__((ext_vector_type(4)));
typedef int   i32x4 __attribute__((ext_vector_type(4)));
typedef __bf16 bf16x8 __attribute__((ext_vector_type(8)));

#define NN 8192
#define DDIM 128

// ---- stash layout inside d_out (bytes) ----
// A'(8192x512B, swizzled [hi|lo] bf16) = C rows 0..127
// B'(8192x512B)                        = C rows 128..255
// norms n1[8192],n2[8192] f32          = last 64KB = C rows 8190..8191
#define APRIME_OFF 0u
#define BPRIME_OFF (8192u*512u)
#define NORM_OFF   (268435456u - 65536u)

__device__ __forceinline__ uint32_t pk2(__bf16 a, __bf16 b) {
    return (uint32_t)__builtin_bit_cast(unsigned short, a)
         | ((uint32_t)__builtin_bit_cast(unsigned short, b) << 16);
}

__device__ __forceinline__ void gload_lds16(const void* g, void* l) {
    __builtin_amdgcn_global_load_lds(
        (const __attribute__((address_space(1))) uint32_t*)g,
        (__attribute__((address_space(3))) uint32_t*)l,
        16, 0, 0);
}

// ---------------- launch 1: prep — split each row ONCE ----------------
// Writes [hi(128)|lo(128)] bf16 per row, 16B units XOR-swizzled by (row&7)
// within each 8-unit chunk group so the GEMM's LDS reads are conflict-free.
__global__ __launch_bounds__(256) void prep_kernel(
    const float* __restrict__ X1, const float* __restrict__ X2,
    const float* __restrict__ log_l, char* __restrict__ outbuf)
{
    int t = threadIdx.x, wave = t >> 6, lane = t & 63;
    int row = blockIdx.x * 4 + wave;          // 0..16383
    const float* X; uint32_t base; float* nrm;
    if (row < NN) {
        X = X1 + (size_t)row * DDIM;
        base = APRIME_OFF + (uint32_t)row * 512u;
        nrm = (float*)(outbuf + NORM_OFF) + row;
    } else {
        int r2 = row - NN;
        X = X2 + (size_t)r2 * DDIM;
        base = BPRIME_OFF + (uint32_t)r2 * 512u;
        nrm = (float*)(outbuf + NORM_OFF) + NN + r2;
    }
    int c0 = lane * 2;
    float2 x = *(const float2*)(X + c0);
    float a0 = x.x * __expf(-log_l[c0]);
    float a1 = x.y * __expf(-log_l[c0 + 1]);
    float ss = a0 * a0 + a1 * a1;
    #pragma unroll
    for (int o = 32; o; o >>= 1) ss += __shfl_down(ss, o);
    if (lane == 0) *nrm = ss;
    __bf16 h0 = (__bf16)a0, h1 = (__bf16)a1;                 // RNE hi (verified)
    __bf16 l0 = (__bf16)(a0 - (float)h0), l1 = (__bf16)(a1 - (float)h1);
    int j = lane >> 2;                                       // logical 16B unit 0..15
    int phys = (j & 8) | ((j & 7) ^ (row & 7));              // swizzled position
    uint32_t off = base + (uint32_t)phys * 16u + (uint32_t)(lane & 3) * 4u;
    *(uint32_t*)(outbuf + off)        = pk2(h0, h1);         // hi block
    *(uint32_t*)(outbuf + off + 256u) = pk2(l0, l1);         // lo block (+128 bf16)
}

// ---------------- launch 2: fast — m97-clone 4-term K=256 GEMM ----------------
// Single-buffered LDS (A 16K | B 16K), global_load_lds staging (linear dest,
// source already swizzled by prep), conflict-free swizzled ds_read_b128,
// swapped-operand MFMA (verified R7 C-layout), fused epilogue, norms from stash.
__global__ __launch_bounds__(256, 3) void fast_kernel(
    const char* __restrict__ stash,
    const int* __restrict__ task1, const int* __restrict__ task2,
    const float* __restrict__ log_theta_l, const float* __restrict__ bparam,
    float* __restrict__ C)
{
    __shared__ __align__(16) char smem[32768];
    const int t = threadIdx.x;
    const int lane = t & 63, wv = t >> 6;
    const int wr = wv >> 1, wc = wv & 1;
    const int lr = lane & 15, lg = lane >> 4;

    // bijective XCD swizzle over 3904 = 8*488 blocks; tm in 2..62
    int wg = blockIdx.x;
    int swz = (wg & 7) * 488 + (wg >> 3);
    int tm = 2 + (swz >> 6);
    int tn = swz & 63;

    const char* Abase = stash + APRIME_OFF + (size_t)tm * 128 * 512;
    const char* Bbase = stash + BPRIME_OFF + (size_t)tn * 128 * 512;

    f32x4 acc[4][4];
    #pragma unroll
    for (int i = 0; i < 4; ++i)
        #pragma unroll
        for (int j = 0; j < 4; ++j) acc[i][j] = (f32x4){0.f, 0.f, 0.f, 0.f};

    // stage chunk c (K cols 64c..64c+63): 16KB per side, unit-for-unit linear copy
    #define STAGE(c) do {                                                         \
        _Pragma("unroll")                                                         \
        for (int i = 0; i < 4; ++i) {                                             \
            int l = t + i * 256;                                                  \
            gload_lds16(Abase + (size_t)(l >> 3) * 512 + (c) * 128 + (l & 7) * 16,\
                        smem + l * 16);                                           \
            gload_lds16(Bbase + (size_t)(l >> 3) * 512 + (c) * 128 + (l & 7) * 16,\
                        smem + 16384 + l * 16);                                   \
        }                                                                         \
    } while (0)

    #define FRAGMM() do {                                                         \
        _Pragma("unroll")                                                         \
        for (int ks = 0; ks < 2; ++ks) {                                          \
            bf16x8 af[4], bfr[4];                                                 \
            _Pragma("unroll")                                                     \
            for (int mi = 0; mi < 4; ++mi) {                                      \
                int row = wr * 64 + mi * 16 + lr;                                 \
                af[mi] = *(const bf16x8*)(smem + row * 128                        \
                          + (((ks * 4 + lg) ^ (row & 7)) * 16));                  \
            }                                                                     \
            _Pragma("unroll")                                                     \
            for (int ni = 0; ni < 4; ++ni) {                                      \
                int row = wc * 64 + ni * 16 + lr;                                 \
                bfr[ni] = *(const bf16x8*)(smem + 16384 + row * 128               \
                          + (((ks * 4 + lg) ^ (row & 7)) * 16));                  \
            }                                                                     \
            _Pragma("unroll")                                                     \
            for (int mi = 0; mi < 4; ++mi)                                        \
                _Pragma("unroll")                                                 \
                for (int ni = 0; ni < 4; ++ni)                                    \
                    acc[mi][ni] = __builtin_amdgcn_mfma_f32_16x16x32_bf16(        \
                        bfr[ni], af[mi], acc[mi][ni], 0, 0, 0);                   \
        }                                                                         \
    } while (0)

    STAGE(0);
    __syncthreads();           // drains gload_lds (vmcnt) — data ready
    FRAGMM();
    #pragma unroll
    for (int c = 1; c < 4; ++c) {
        __syncthreads();       // prior reads done before overwrite
        STAGE(c);
        __syncthreads();       // staging complete
        FRAGMM();
    }

    // ---- epilogue (verified R7 mapping); norms/tasks from global ----
    const float* n1g = (const float*)(stash + NORM_OFF);
    const float* n2g = n1g + NN;
    float logt = log_theta_l[0];
    float bb = bparam[0];
    float lam = fminf(fmaxf(2.f / (1.f + __expf(bb)) - 1.f, 0.f), 1.f);
    int rbase = tm * 128, cbase = tn * 128;

    #pragma unroll
    for (int mi = 0; mi < 4; ++mi) {
        int rowl = wr * 64 + mi * 16 + lr;
        float n1v = n1g[rbase + rowl];
        int t1v = task1[rbase + rowl];
        #pragma unroll
        for (int ni = 0; ni < 4; ++ni) {
            int coll = wc * 64 + ni * 16 + lg * 4;
            f32x4 n2v = *(const f32x4*)(n2g + cbase + coll);
            i32x4 t2v = *(const i32x4*)(task2 + cbase + coll);
            f32x4 kv;
            #pragma unroll
            for (int rix = 0; rix < 4; ++rix) {
                float s = fmaxf(n1v + n2v[rix] - 2.f * acc[mi][ni][rix], 0.f);
                float k = __expf(fmaf(-0.5f, s, logt));
                kv[rix] = (t1v != t2v[rix]) ? k * lam : k;
            }
            *(f32x4*)(C + (size_t)(rbase + rowl) * NN + cbase + coll) = kv;
        }
    }
    #undef STAGE
    #undef FRAGMM
}

// ---------------- launch 3: slow — R7 kernel verbatim for tm in {0,1,63} ----------------
#define RSTRIDE 80
#define S_AH 0
#define S_AL 10240
#define S_BH 20480
#define S_BL 30720
#define S_ILS 40960
#define S_N1  41472
#define S_N2  41984
#define S_TOT 42496

__device__ __forceinline__ void split4(f32x4 x, uint2& hi, uint2& lo) {
    __bf16 h0 = (__bf16)x[0], h1 = (__bf16)x[1], h2 = (__bf16)x[2], h3 = (__bf16)x[3];
    hi.x = pk2(h0, h1); hi.y = pk2(h2, h3);
    __bf16 l0 = (__bf16)(x[0] - (float)h0);
    __bf16 l1 = (__bf16)(x[1] - (float)h1);
    __bf16 l2 = (__bf16)(x[2] - (float)h2);
    __bf16 l3 = (__bf16)(x[3] - (float)h3);
    lo.x = pk2(l0, l1); lo.y = pk2(l2, l3);
}

__device__ __forceinline__ void lds_barrier() {
    asm volatile("s_waitcnt lgkmcnt(0)" ::: "memory");
    __builtin_amdgcn_sched_barrier(0);
    __builtin_amdgcn_s_barrier();
    __builtin_amdgcn_sched_barrier(0);
}

__global__ __launch_bounds__(256, 3) void slow_kernel(
    const float* __restrict__ X1, const float* __restrict__ X2,
    const float* __restrict__ log_l,
    const float* __restrict__ log_theta_l, const float* __restrict__ bparam,
    const int* __restrict__ task1, const int* __restrict__ task2,
    float* __restrict__ C)
{
    __shared__ __align__(16) char smem[S_TOT];
    float* const ils = (float*)(smem + S_ILS);
    float* const n1s = (float*)(smem + S_N1);
    float* const n2s = (float*)(smem + S_N2);

    const int t = threadIdx.x;
    const int lane = t & 63;
    const int wv = t >> 6;
    const int wr = wv >> 1, wc = wv & 1;
    const int lr = lane & 15, lg = lane >> 4;
    const int kq = t & 7;
    const int rg = t >> 3;

    int wg = blockIdx.x;                 // 0..191
    int tsel = wg >> 6;
    int tm = (tsel == 2) ? 63 : tsel;
    int tn = wg & 63;

    const float* Ag = X1 + (size_t)tm * 128 * DDIM;
    const float* Bg = X2 + (size_t)tn * 128 * DDIM;

    if (t < 128) ils[t] = __expf(-log_l[t]);

    f32x4 aV[4], bV[4];
    #pragma unroll
    for (int e = 0; e < 4; ++e) {
        aV[e] = *(const f32x4*)(Ag + (size_t)(e * 32 + rg) * DDIM + kq * 4);
        bV[e] = *(const f32x4*)(Bg + (size_t)(e * 32 + rg) * DDIM + kq * 4);
    }
    __syncthreads();

    float nA[4] = {0.f, 0.f, 0.f, 0.f};
    float nB[4] = {0.f, 0.f, 0.f, 0.f};
    f32x4 acc[4][4];
    #pragma unroll
    for (int i = 0; i < 4; ++i)
        #pragma unroll
        for (int j = 0; j < 4; ++j) acc[i][j] = (f32x4){0.f, 0.f, 0.f, 0.f};

    for (int c = 0; c < 4; ++c) {
        {
            f32x4 il4 = *(const f32x4*)(ils + c * 32 + kq * 4);
            #pragma unroll
            for (int e = 0; e < 4; ++e) {
                int rr = e * 32 + rg;
                f32x4 xa = aV[e] * il4;
                f32x4 xb = bV[e] * il4;
                nA[e] += xa[0]*xa[0] + xa[1]*xa[1] + xa[2]*xa[2] + xa[3]*xa[3];
                nB[e] += xb[0]*xb[0] + xb[1]*xb[1] + xb[2]*xb[2] + xb[3]*xb[3];
                uint2 hA, lA, hB, lB;
                split4(xa, hA, lA);
                split4(xb, hB, lB);
                int boff = rr * RSTRIDE + kq * 8;
                *(uint2*)(smem + S_AH + boff) = hA;
                *(uint2*)(smem + S_AL + boff) = lA;
                *(uint2*)(smem + S_BH + boff) = hB;
                *(uint2*)(smem + S_BL + boff) = lB;
            }
        }
        if (c < 3) {
            #pragma unroll
            for (int e = 0; e < 4; ++e) {
                aV[e] = *(const f32x4*)(Ag + (size_t)(e * 32 + rg) * DDIM + (c + 1) * 32 + kq * 4);
                bV[e] = *(const f32x4*)(Bg + (size_t)(e * 32 + rg) * DDIM + (c + 1) * 32 + kq * 4);
            }
        }
        lds_barrier();
        {
            bf16x8 ah[4], bh[4], xf[4];
            #pragma unroll
            for (int mi = 0; mi < 4; ++mi) {
                int off = (wr * 64 + mi * 16 + lr) * RSTRIDE + lg * 16;
                ah[mi] = *(const bf16x8*)(smem + S_AH + off);
            }
            #pragma unroll
            for (int ni = 0; ni < 4; ++ni) {
                int off = (wc * 64 + ni * 16 + lr) * RSTRIDE + lg * 16;
                bh[ni] = *(const bf16x8*)(smem + S_BH + off);
            }
            #pragma unroll
            for (int mi = 0; mi < 4; ++mi)
                #pragma unroll
                for (int ni = 0; ni < 4; ++ni)
                    acc[mi][ni] = __builtin_amdgcn_mfma_f32_16x16x32_bf16(bh[ni], ah[mi], acc[mi][ni], 0, 0, 0);
            #pragma unroll
            for (int mi = 0; mi < 4; ++mi) {
                int off = (wr * 64 + mi * 16 + lr) * RSTRIDE + lg * 16;
                xf[mi] = *(const bf16x8*)(smem + S_AL + off);
            }
            #pragma unroll
            for (int mi = 0; mi < 4; ++mi)
                #pragma unroll
                for (int ni = 0; ni < 4; ++ni)
                    acc[mi][ni] = __builtin_amdgcn_mfma_f32_16x16x32_bf16(bh[ni], xf[mi], acc[mi][ni], 0, 0, 0);
            #pragma unroll
            for (int ni = 0; ni < 4; ++ni) {
                int off = (wc * 64 + ni * 16 + lr) * RSTRIDE + lg * 16;
                xf[ni] = *(const bf16x8*)(smem + S_BL + off);
            }
            #pragma unroll
            for (int mi = 0; mi < 4; ++mi)
                #pragma unroll
                for (int ni = 0; ni < 4; ++ni)
                    acc[mi][ni] = __builtin_amdgcn_mfma_f32_16x16x32_bf16(xf[ni], ah[mi], acc[mi][ni], 0, 0, 0);
        }
        lds_barrier();
    }

    #pragma unroll
    for (int e = 0; e < 4; ++e) {
        #pragma unroll
        for (int off = 1; off < 8; off <<= 1) {
            nA[e] += __shfl_xor(nA[e], off);
            nB[e] += __shfl_xor(nB[e], off);
        }
    }
    if (kq == 0) {
        #pragma unroll
        for (int e = 0; e < 4; ++e) {
            n1s[e * 32 + rg] = nA[e];
            n2s[e * 32 + rg] = nB[e];
        }
    }
    __syncthreads();

    float logt = log_theta_l[0];
    float bb = bparam[0];
    float lam = fminf(fmaxf(2.f / (1.f + __expf(bb)) - 1.f, 0.f), 1.f);
    int rbase = tm * 128, cbase = tn * 128;

    #pragma unroll
    for (int mi = 0; mi < 4; ++mi) {
        int rowl = wr * 64 + mi * 16 + lr;
        float n1v = n1s[rowl];
        int t1v = task1[rbase + rowl];
        #pragma unroll
        for (int ni = 0; ni < 4; ++ni) {
            int coll = wc * 64 + ni * 16 + lg * 4;
            f32x4 n2v = *(const f32x4*)(n2s + coll);
            i32x4 t2v = *(const i32x4*)(task2 + cbase + coll);
            f32x4 kv;
            #pragma unroll
            for (int rix = 0; rix < 4; ++rix) {
                float s = fmaxf(n1v + n2v[rix] - 2.f * acc[mi][ni][rix], 0.f);
                float k = __expf(fmaf(-0.5f, s, logt));
                kv[rix] = (t1v != t2v[rix]) ? k * lam : k;
            }
            *(f32x4*)(C + (size_t)(rbase + rowl) * NN + cbase + coll) = kv;
        }
    }
}

extern "C" void kernel_launch(void* const* d_in, const int* in_sizes, int n_in,
                              void* d_out, int out_size, void* d_ws, size_t ws_size,
                              hipStream_t stream)
{
    const float* X1 = (const float*)d_in[0];
    const float* X2 = (const float*)d_in[1];
    const float* log_l = (const float*)d_in[2];
    const float* log_theta = (const float*)d_in[3];
    const float* bp = (const float*)d_in[4];
    const int* t1 = (const int*)d_in[5];
    const int* t2 = (const int*)d_in[6];
    float* C = (float*)d_out;
    (void)d_ws; (void)ws_size; (void)in_sizes; (void)n_in; (void)out_size;

    prep_kernel<<<4096, 256, 0, stream>>>(X1, X2, log_l, (char*)d_out);
    fast_kernel<<<3904, 256, 0, stream>>>((const char*)d_out, t1, t2, log_theta, bp, C);
    slow_kernel<<<192, 256, 0, stream>>>(X1, X2, log_l, log_theta, bp, t1, t2, C);
}